// Round 1
// baseline (504.029 us; speedup 1.0000x reference)
//
#include <hip/hip_runtime.h>
#include <cstdint>
#include <cstddef>

#define B_ 4
#define T_ 2048
#define C_ 768
#define H_ 12
#define D_ 64
#define FF_ 3072

typedef __attribute__((ext_vector_type(4))) float f32x4;
typedef __attribute__((ext_vector_type(8))) short s16x8;
typedef __attribute__((ext_vector_type(4))) short s16x4;

static __device__ __forceinline__ short f2bf(float f) {
  union { float fv; unsigned u; } v; v.fv = f;
  unsigned r = v.u + 0x7FFFu + ((v.u >> 16) & 1u);  // RNE
  return (short)(r >> 16);
}

// ---------- weight convert+transpose: in[K,N] f32 -> out[N,K] bf16 ----------
__global__ __launch_bounds__(256) void wconv(const float* __restrict__ in,
                                             short* __restrict__ out,
                                             int K, int N) {
  __shared__ float tile[32][33];
  int tk = blockIdx.x * 32, tn = blockIdx.y * 32;
  int lx = threadIdx.x & 31, ly = threadIdx.x >> 5;
#pragma unroll
  for (int i = 0; i < 4; ++i)
    tile[ly + i * 8][lx] = in[(size_t)(tk + ly + i * 8) * N + tn + lx];
  __syncthreads();
#pragma unroll
  for (int i = 0; i < 4; ++i)
    out[(size_t)(tn + ly + i * 8) * K + tk + lx] = f2bf(tile[lx][ly + i * 8]);
}

// ---------- layernorm: x[rows,768] f32 -> bf16 ----------
__global__ __launch_bounds__(256) void ln_kernel(const float* __restrict__ x,
                                                 const float* __restrict__ w,
                                                 const float* __restrict__ b,
                                                 short* __restrict__ out) {
  int row = blockIdx.x, tid = threadIdx.x;
  const float* xr = x + (size_t)row * 768;
  float v0 = xr[tid], v1 = xr[tid + 256], v2 = xr[tid + 512];
  float s = v0 + v1 + v2;
#pragma unroll
  for (int o = 32; o > 0; o >>= 1) s += __shfl_down(s, o);
  __shared__ float r1[4], r2[4];
  if ((tid & 63) == 0) r1[tid >> 6] = s;
  __syncthreads();
  float mean = (r1[0] + r1[1] + r1[2] + r1[3]) * (1.f / 768.f);
  float d0 = v0 - mean, d1 = v1 - mean, d2 = v2 - mean;
  float q = d0 * d0 + d1 * d1 + d2 * d2;
#pragma unroll
  for (int o = 32; o > 0; o >>= 1) q += __shfl_down(q, o);
  if ((tid & 63) == 0) r2[tid >> 6] = q;
  __syncthreads();
  float var = (r2[0] + r2[1] + r2[2] + r2[3]) * (1.f / 768.f);
  float rstd = rsqrtf(var + 1e-5f);
  short* orow = out + (size_t)row * 768;
  orow[tid]       = f2bf(d0 * rstd * w[tid]       + b[tid]);
  orow[tid + 256] = f2bf(d1 * rstd * w[tid + 256] + b[tid + 256]);
  orow[tid + 512] = f2bf(d2 * rstd * w[tid + 512] + b[tid + 512]);
}

// ---------- GEMM: C[M,N] = A[M,K](bf16) * Bt[N,K](bf16)^T + bias, fused epilogues ----------
// MODE 0: qkv scatter (bias, q*=0.125, -> per-head bf16 Q/K/V [B,H,T,D])
// MODE 1: bias + residual(res f32) -> f32 out
// MODE 2: bias + relu -> bf16 out
// MODE 3: bias + residual(res f32) -> f32 out
template <int MODE>
__global__ __launch_bounds__(256) void gemm_bt(
    const short* __restrict__ A, const short* __restrict__ Bt,
    const float* __restrict__ bias, const float* __restrict__ res,
    void* __restrict__ out,
    short* __restrict__ dq, short* __restrict__ dk, short* __restrict__ dv,
    int M, int N, int K) {
  __shared__ short As[128 * 32];
  __shared__ short Bs[128 * 32];
  int tid = threadIdx.x;
  int lane = tid & 63;
  int wm = tid >> 7;            // wave / 2
  int wn = (tid >> 6) & 1;      // wave % 2
  const short* Ab = A + (size_t)blockIdx.x * 128 * K;
  const short* Bb = Bt + (size_t)blockIdx.y * 128 * K;
  f32x4 acc[4][4] = {};
  int i15 = lane & 15, g8 = (lane >> 4) << 3;
  int nk = K >> 5;
  for (int kt = 0; kt < nk; ++kt) {
    int kof = kt << 5;
#pragma unroll
    for (int i = 0; i < 2; ++i) {
      int s = tid + i * 256;
      int row = s >> 2, kk = (s & 3) << 3;
      __builtin_amdgcn_global_load_lds(
          (const __attribute__((address_space(1))) unsigned*)(Ab + (size_t)row * K + kof + kk),
          (__attribute__((address_space(3))) unsigned*)(As + s * 8), 16, 0, 0);
      __builtin_amdgcn_global_load_lds(
          (const __attribute__((address_space(1))) unsigned*)(Bb + (size_t)row * K + kof + kk),
          (__attribute__((address_space(3))) unsigned*)(Bs + s * 8), 16, 0, 0);
    }
    __syncthreads();
    s16x8 af[4], bfr[4];
#pragma unroll
    for (int m = 0; m < 4; ++m)
      af[m] = *(const s16x8*)(As + (wm * 64 + m * 16 + i15) * 32 + g8);
#pragma unroll
    for (int n = 0; n < 4; ++n)
      bfr[n] = *(const s16x8*)(Bs + (wn * 64 + n * 16 + i15) * 32 + g8);
#pragma unroll
    for (int m = 0; m < 4; ++m)
#pragma unroll
      for (int n = 0; n < 4; ++n)
        acc[m][n] = __builtin_amdgcn_mfma_f32_16x16x32_bf16(af[m], bfr[n], acc[m][n], 0, 0, 0);
    __syncthreads();
  }
  int row0 = blockIdx.x * 128 + wm * 64;
  int col0 = blockIdx.y * 128 + wn * 64;
#pragma unroll
  for (int m = 0; m < 4; ++m) {
#pragma unroll
    for (int n = 0; n < 4; ++n) {
      int col = col0 + n * 16 + i15;
      float bv = bias[col];
#pragma unroll
      for (int r = 0; r < 4; ++r) {
        int row = row0 + m * 16 + ((lane >> 4) << 2) + r;
        float val = acc[m][n][r] + bv;
        if constexpr (MODE == 0) {
          int sect = col / 768;            // 0=q 1=k 2=v
          int wi = col - sect * 768;
          int hh = wi >> 6, dd = wi & 63;
          int bb = row >> 11, tt = row & 2047;
          size_t o = (((size_t)bb * H_ + hh) * T_ + tt) * D_ + dd;
          short ov = f2bf(sect == 0 ? val * 0.125f : val);
          (sect == 0 ? dq : sect == 1 ? dk : dv)[o] = ov;
        } else if constexpr (MODE == 2) {
          ((short*)out)[(size_t)row * N + col] = f2bf(val > 0.f ? val : 0.f);
        } else {
          ((float*)out)[(size_t)row * N + col] = val + res[(size_t)row * N + col];
        }
      }
    }
  }
}

// ---------- causal flash attention ----------
// Q/K/V: [B*H, T, D] bf16, Q pre-scaled by 1/8. Out: [B,T,C] bf16.
// Block = 64 q-rows of one (b,h); wave = 16 q-rows. Key tiles of 32.
// S^T computed via mfma(K_perm, Q); permuted K rows make the S^T accumulator
// fragment directly usable as the B operand of the K=32 PV mfma.
__global__ __launch_bounds__(256) void attn_kernel(const short* __restrict__ Qb,
                                                   const short* __restrict__ Kb,
                                                   const short* __restrict__ Vb,
                                                   short* __restrict__ Ob) {
  __shared__ short Vt[64 * 32];  // [d][key] transposed V tile
  int bx = blockIdx.x, bh = blockIdx.y;
  int bb = bh / H_, hh = bh - bb * H_;
  int tid = threadIdx.x, lane = tid & 63, wv = tid >> 6;
  int q0 = bx * 64 + wv * 16;
  const short* Qp = Qb + (size_t)bh * T_ * D_;
  const short* Kp = Kb + (size_t)bh * T_ * D_;
  const short* Vp = Vb + (size_t)bh * T_ * D_;
  int i15 = lane & 15, g = lane >> 4, g8 = g << 3;
  int qrow = q0 + i15;
  s16x8 qf0 = *(const s16x8*)(Qp + (size_t)qrow * D_ + g8);
  s16x8 qf1 = *(const s16x8*)(Qp + (size_t)qrow * D_ + 32 + g8);
  f32x4 oacc[4] = {};
  float mrun = -1e30f, lrun = 0.f;
  int ntiles = 2 * bx + 2;                 // all waves same trip count
  int vk = tid & 31, vd = (tid >> 5) << 3;
  int keyA0 = ((i15 >> 2) << 3) + (i15 & 3);  // perm: row i -> key (i/4)*8 + i%4
  for (int kt = 0; kt < ntiles; ++kt) {
    int k0 = kt << 5;
    __syncthreads();
    {
      s16x8 vv = *(const s16x8*)(Vp + (size_t)(k0 + vk) * D_ + vd);
#pragma unroll
      for (int j = 0; j < 8; ++j) Vt[(vd + j) * 32 + vk] = vv[j];
    }
    __syncthreads();
    const short* KpA = Kp + (size_t)(k0 + keyA0) * D_;
    s16x8 kA0 = *(const s16x8*)(KpA + g8);
    s16x8 kA1 = *(const s16x8*)(KpA + 32 + g8);
    const short* KpB = KpA + 4 * D_;
    s16x8 kB0 = *(const s16x8*)(KpB + g8);
    s16x8 kB1 = *(const s16x8*)(KpB + 32 + g8);
    f32x4 sA = {}, sB = {};
    sA = __builtin_amdgcn_mfma_f32_16x16x32_bf16(kA0, qf0, sA, 0, 0, 0);
    sA = __builtin_amdgcn_mfma_f32_16x16x32_bf16(kA1, qf1, sA, 0, 0, 0);
    sB = __builtin_amdgcn_mfma_f32_16x16x32_bf16(kB0, qf0, sB, 0, 0, 0);
    sB = __builtin_amdgcn_mfma_f32_16x16x32_bf16(kB1, qf1, sB, 0, 0, 0);
    // lane holds S^T for keys k0 + g*8 + {0..7} (A tile r=0..3, B tile r=0..3), q-row = q0+i15
    int kb = k0 + g8;
    float sa[8];
#pragma unroll
    for (int r = 0; r < 4; ++r) {
      sa[r]     = (kb + r     <= qrow) ? sA[r] : -1e30f;
      sa[4 + r] = (kb + 4 + r <= qrow) ? sB[r] : -1e30f;
    }
    float tmx = sa[0];
#pragma unroll
    for (int r = 1; r < 8; ++r) tmx = fmaxf(tmx, sa[r]);
    tmx = fmaxf(tmx, __shfl_xor(tmx, 16));
    tmx = fmaxf(tmx, __shfl_xor(tmx, 32));
    float mnew = fmaxf(mrun, tmx);
    float scl = __expf(mrun - mnew);
    float ps = 0.f;
    s16x8 pf;
#pragma unroll
    for (int r = 0; r < 8; ++r) {
      float p = __expf(sa[r] - mnew);
      ps += p;
      pf[r] = f2bf(p);
    }
    ps += __shfl_xor(ps, 16);
    ps += __shfl_xor(ps, 32);
    lrun = lrun * scl + ps;
    mrun = mnew;
#pragma unroll
    for (int mt = 0; mt < 4; ++mt) {
#pragma unroll
      for (int r = 0; r < 4; ++r) oacc[mt][r] *= scl;
      s16x8 vf = *(const s16x8*)(Vt + (mt * 16 + i15) * 32 + g8);
      oacc[mt] = __builtin_amdgcn_mfma_f32_16x16x32_bf16(vf, pf, oacc[mt], 0, 0, 0);
    }
  }
  float inv = 1.f / lrun;
  short* op = Ob + ((size_t)(bb * T_ + qrow)) * C_ + hh * D_ + (g << 2);
#pragma unroll
  for (int mt = 0; mt < 4; ++mt) {
    s16x4 o4;
#pragma unroll
    for (int r = 0; r < 4; ++r) o4[r] = f2bf(oacc[mt][r] * inv);
    *(s16x4*)(op + mt * 16) = o4;
  }
}

extern "C" void kernel_launch(void* const* d_in, const int* in_sizes, int n_in,
                              void* d_out, int out_size, void* d_ws, size_t ws_size,
                              hipStream_t stream) {
  const float* x     = (const float*)d_in[0];
  const float* ln1_w = (const float*)d_in[1];
  const float* ln1_b = (const float*)d_in[2];
  const float* qkv_w = (const float*)d_in[3];
  const float* qkv_b = (const float*)d_in[4];
  const float* out_w = (const float*)d_in[5];
  const float* out_b = (const float*)d_in[6];
  const float* ln2_w = (const float*)d_in[7];
  const float* ln2_b = (const float*)d_in[8];
  const float* ff1_w = (const float*)d_in[9];
  const float* ff1_b = (const float*)d_in[10];
  const float* ff2_w = (const float*)d_in[11];
  const float* ff2_b = (const float*)d_in[12];

  char* ws = (char*)d_ws;
  short* Wqkv = (short*)(ws + 0);                       // [2304,768]
  short* Wout = (short*)(ws + 3538944);                 // [768,768]
  short* Wff1 = (short*)(ws + 4718592);                 // [3072,768]
  short* Wff2 = (short*)(ws + 9437184);                 // [768,3072]
  short* Hbuf = (short*)(ws + 14155776);                // [8192,768] bf16
  short* Qb   = (short*)(ws + 26738688);                // [B,H,T,D] bf16
  short* Kb   = Qb + 6291456;
  short* Vb   = Kb + 6291456;
  short* Ob   = Vb + 6291456;                           // [B,T,C] bf16
  short* FFH  = Qb;                                     // alias: [8192,3072] bf16 (Q/K/V/O dead)
  float* xout = (float*)d_out;                          // also x1 residual buffer

  wconv<<<dim3(24, 72), 256, 0, stream>>>(qkv_w, Wqkv, 768, 2304);
  wconv<<<dim3(24, 24), 256, 0, stream>>>(out_w, Wout, 768, 768);
  wconv<<<dim3(24, 96), 256, 0, stream>>>(ff1_w, Wff1, 768, 3072);
  wconv<<<dim3(96, 24), 256, 0, stream>>>(ff2_w, Wff2, 3072, 768);

  ln_kernel<<<8192, 256, 0, stream>>>(x, ln1_w, ln1_b, Hbuf);
  gemm_bt<0><<<dim3(64, 18), 256, 0, stream>>>(Hbuf, Wqkv, qkv_b, nullptr, nullptr,
                                               Qb, Kb, Vb, 8192, 2304, 768);
  attn_kernel<<<dim3(32, 48), 256, 0, stream>>>(Qb, Kb, Vb, Ob);
  gemm_bt<1><<<dim3(64, 6), 256, 0, stream>>>(Ob, Wout, out_b, x, xout,
                                              nullptr, nullptr, nullptr, 8192, 768, 768);
  ln_kernel<<<8192, 256, 0, stream>>>(xout, ln2_w, ln2_b, Hbuf);
  gemm_bt<2><<<dim3(64, 24), 256, 0, stream>>>(Hbuf, Wff1, ff1_b, nullptr, FFH,
                                               nullptr, nullptr, nullptr, 8192, 3072, 768);
  gemm_bt<3><<<dim3(64, 6), 256, 0, stream>>>(FFH, Wff2, ff2_b, xout, xout,
                                              nullptr, nullptr, nullptr, 8192, 768, 3072);
}

// Round 2
// 416.987 us; speedup vs baseline: 1.2087x; 1.2087x over previous
//
#include <hip/hip_runtime.h>
#include <cstdint>
#include <cstddef>

#define B_ 4
#define T_ 2048
#define C_ 768
#define H_ 12
#define D_ 64
#define FF_ 3072

typedef __attribute__((ext_vector_type(4))) float f32x4;
typedef __attribute__((ext_vector_type(8))) short s16x8;
typedef __attribute__((ext_vector_type(4))) short s16x4;

static __device__ __forceinline__ short f2bf(float f) {
  union { float fv; unsigned u; } v; v.fv = f;
  unsigned r = v.u + 0x7FFFu + ((v.u >> 16) & 1u);  // RNE
  return (short)(r >> 16);
}

// ---------- weight convert+transpose: in[K,N] f32 -> out[N,K] bf16 ----------
__global__ __launch_bounds__(256) void wconv(const float* __restrict__ in,
                                             short* __restrict__ out,
                                             int K, int N) {
  __shared__ float tile[32][33];
  int tk = blockIdx.x * 32, tn = blockIdx.y * 32;
  int lx = threadIdx.x & 31, ly = threadIdx.x >> 5;
#pragma unroll
  for (int i = 0; i < 4; ++i)
    tile[ly + i * 8][lx] = in[(size_t)(tk + ly + i * 8) * N + tn + lx];
  __syncthreads();
#pragma unroll
  for (int i = 0; i < 4; ++i)
    out[(size_t)(tn + ly + i * 8) * K + tk + lx] = f2bf(tile[lx][ly + i * 8]);
}

// ---------- layernorm: x[rows,768] f32 -> bf16 ----------
__global__ __launch_bounds__(256) void ln_kernel(const float* __restrict__ x,
                                                 const float* __restrict__ w,
                                                 const float* __restrict__ b,
                                                 short* __restrict__ out) {
  int row = blockIdx.x, tid = threadIdx.x;
  const float* xr = x + (size_t)row * 768;
  float v0 = xr[tid], v1 = xr[tid + 256], v2 = xr[tid + 512];
  float s = v0 + v1 + v2;
#pragma unroll
  for (int o = 32; o > 0; o >>= 1) s += __shfl_down(s, o);
  __shared__ float r1[4], r2[4];
  if ((tid & 63) == 0) r1[tid >> 6] = s;
  __syncthreads();
  float mean = (r1[0] + r1[1] + r1[2] + r1[3]) * (1.f / 768.f);
  float d0 = v0 - mean, d1 = v1 - mean, d2 = v2 - mean;
  float q = d0 * d0 + d1 * d1 + d2 * d2;
#pragma unroll
  for (int o = 32; o > 0; o >>= 1) q += __shfl_down(q, o);
  if ((tid & 63) == 0) r2[tid >> 6] = q;
  __syncthreads();
  float var = (r2[0] + r2[1] + r2[2] + r2[3]) * (1.f / 768.f);
  float rstd = rsqrtf(var + 1e-5f);
  short* orow = out + (size_t)row * 768;
  orow[tid]       = f2bf(d0 * rstd * w[tid]       + b[tid]);
  orow[tid + 256] = f2bf(d1 * rstd * w[tid + 256] + b[tid + 256]);
  orow[tid + 512] = f2bf(d2 * rstd * w[tid + 512] + b[tid + 512]);
}

// ---------- GEMM: C[M,N] = A[M,K](bf16) * Bt[N,K](bf16)^T + bias, fused epilogues ----------
template <int MODE>
__global__ __launch_bounds__(256) void gemm_bt(
    const short* __restrict__ A, const short* __restrict__ Bt,
    const float* __restrict__ bias, const float* __restrict__ res,
    void* __restrict__ out,
    short* __restrict__ dq, short* __restrict__ dk, short* __restrict__ dv,
    int M, int N, int K) {
  __shared__ short As[128 * 32];
  __shared__ short Bs[128 * 32];
  int tid = threadIdx.x;
  int lane = tid & 63;
  int wm = tid >> 7;
  int wn = (tid >> 6) & 1;
  const short* Ab = A + (size_t)blockIdx.x * 128 * K;
  const short* Bb = Bt + (size_t)blockIdx.y * 128 * K;
  f32x4 acc[4][4] = {};
  int i15 = lane & 15, g8 = (lane >> 4) << 3;
  int nk = K >> 5;
  for (int kt = 0; kt < nk; ++kt) {
    int kof = kt << 5;
#pragma unroll
    for (int i = 0; i < 2; ++i) {
      int s = tid + i * 256;
      int row = s >> 2, kk = (s & 3) << 3;
      __builtin_amdgcn_global_load_lds(
          (const __attribute__((address_space(1))) unsigned*)(Ab + (size_t)row * K + kof + kk),
          (__attribute__((address_space(3))) unsigned*)(As + s * 8), 16, 0, 0);
      __builtin_amdgcn_global_load_lds(
          (const __attribute__((address_space(1))) unsigned*)(Bb + (size_t)row * K + kof + kk),
          (__attribute__((address_space(3))) unsigned*)(Bs + s * 8), 16, 0, 0);
    }
    __syncthreads();
    s16x8 af[4], bfr[4];
#pragma unroll
    for (int m = 0; m < 4; ++m)
      af[m] = *(const s16x8*)(As + (wm * 64 + m * 16 + i15) * 32 + g8);
#pragma unroll
    for (int n = 0; n < 4; ++n)
      bfr[n] = *(const s16x8*)(Bs + (wn * 64 + n * 16 + i15) * 32 + g8);
#pragma unroll
    for (int m = 0; m < 4; ++m)
#pragma unroll
      for (int n = 0; n < 4; ++n)
        acc[m][n] = __builtin_amdgcn_mfma_f32_16x16x32_bf16(af[m], bfr[n], acc[m][n], 0, 0, 0);
    __syncthreads();
  }
  int row0 = blockIdx.x * 128 + wm * 64;
  int col0 = blockIdx.y * 128 + wn * 64;
#pragma unroll
  for (int m = 0; m < 4; ++m) {
#pragma unroll
    for (int n = 0; n < 4; ++n) {
      int col = col0 + n * 16 + i15;
      float bv = bias[col];
#pragma unroll
      for (int r = 0; r < 4; ++r) {
        int row = row0 + m * 16 + ((lane >> 4) << 2) + r;
        float val = acc[m][n][r] + bv;
        if constexpr (MODE == 0) {
          int sect = col / 768;
          int wi = col - sect * 768;
          int hh = wi >> 6, dd = wi & 63;
          int bb = row >> 11, tt = row & 2047;
          size_t o = (((size_t)bb * H_ + hh) * T_ + tt) * D_ + dd;
          short ov = f2bf(sect == 0 ? val * 0.125f : val);
          (sect == 0 ? dq : sect == 1 ? dk : dv)[o] = ov;
        } else if constexpr (MODE == 2) {
          ((short*)out)[(size_t)row * N + col] = f2bf(val > 0.f ? val : 0.f);
        } else {
          ((float*)out)[(size_t)row * N + col] = val + res[(size_t)row * N + col];
        }
      }
    }
  }
}

// ---------- V transpose: Vb [B,H,T,D] -> VT [B,H,D,T] (bf16) ----------
__global__ __launch_bounds__(256) void vtrans(const short* __restrict__ Vb,
                                              short* __restrict__ VT) {
  __shared__ short tile[64][78];
  int t0 = blockIdx.x * 64, bh = blockIdx.y;
  const short* src = Vb + (size_t)bh * T_ * D_ + (size_t)t0 * D_;
  int tid = threadIdx.x;
  int r = tid >> 2, c4 = (tid & 3) << 4;
  s16x8 a = *(const s16x8*)(src + r * 64 + c4);
  s16x8 b = *(const s16x8*)(src + r * 64 + c4 + 8);
#pragma unroll
  for (int j = 0; j < 8; ++j) { tile[r][c4 + j] = a[j]; tile[r][c4 + 8 + j] = b[j]; }
  __syncthreads();
  int d = tid >> 2, tc = (tid & 3) << 4;
  short* dst = VT + (size_t)bh * D_ * T_ + (size_t)d * T_ + t0 + tc;
  s16x8 o0, o1;
#pragma unroll
  for (int j = 0; j < 8; ++j) { o0[j] = tile[tc + j][d]; o1[j] = tile[tc + 8 + j][d]; }
  *(s16x8*)dst = o0;
  *(s16x8*)(dst + 8) = o1;
}

// ---------- causal flash attention (no LDS, no barriers) ----------
// Q [B,H,T,D] (pre-scaled 1/8), K [B,H,T,D], VT [B,H,D,T] bf16 -> Ob [B,T,C] bf16.
// 4 waves/block, each wave owns 32 q-rows (2 x 16-row subtiles); key tiles of 32.
__global__ __launch_bounds__(256) void attn_kernel(const short* __restrict__ Qb,
                                                   const short* __restrict__ Kb,
                                                   const short* __restrict__ VTb,
                                                   short* __restrict__ Ob) {
  int bx = gridDim.x - 1 - blockIdx.x;   // longest blocks first
  int bh = blockIdx.y;
  int bb = bh / H_, hh = bh - bb * H_;
  int tid = threadIdx.x, lane = tid & 63, wv = tid >> 6;
  int wq0 = bx * 128 + wv * 32;
  const short* Qp = Qb + (size_t)bh * T_ * D_;
  const short* Kp = Kb + (size_t)bh * T_ * D_;
  const short* Vp = VTb + (size_t)bh * D_ * T_;
  int i15 = lane & 15, g = lane >> 4, g8 = g << 3;
  s16x8 qf[2][2];
#pragma unroll
  for (int s = 0; s < 2; ++s) {
    int qrow = wq0 + s * 16 + i15;
    qf[s][0] = *(const s16x8*)(Qp + (size_t)qrow * D_ + g8);
    qf[s][1] = *(const s16x8*)(Qp + (size_t)qrow * D_ + 32 + g8);
  }
  f32x4 oacc[2][4] = {};
  float mrun[2] = {-1e30f, -1e30f}, lrun[2] = {0.f, 0.f};
  int keyA0 = ((i15 >> 2) << 3) + (i15 & 3);  // perm: A-row i -> key (i/4)*8 + i%4
  int nt = (wq0 >> 5) + 1;
  for (int kt = 0; kt < nt; ++kt) {
    int k0 = kt << 5;
    bool maskt = (kt == nt - 1);
    const short* KpA = Kp + (size_t)(k0 + keyA0) * D_;
    s16x8 kA0 = *(const s16x8*)(KpA + g8);
    s16x8 kA1 = *(const s16x8*)(KpA + 32 + g8);
    const short* KpB = KpA + 4 * D_;
    s16x8 kB0 = *(const s16x8*)(KpB + g8);
    s16x8 kB1 = *(const s16x8*)(KpB + 32 + g8);
    s16x8 vf[4];
#pragma unroll
    for (int mt = 0; mt < 4; ++mt)
      vf[mt] = *(const s16x8*)(Vp + (size_t)(mt * 16 + i15) * T_ + k0 + g8);
#pragma unroll
    for (int s = 0; s < 2; ++s) {
      f32x4 sA = {}, sB = {};
      sA = __builtin_amdgcn_mfma_f32_16x16x32_bf16(kA0, qf[s][0], sA, 0, 0, 0);
      sA = __builtin_amdgcn_mfma_f32_16x16x32_bf16(kA1, qf[s][1], sA, 0, 0, 0);
      sB = __builtin_amdgcn_mfma_f32_16x16x32_bf16(kB0, qf[s][0], sB, 0, 0, 0);
      sB = __builtin_amdgcn_mfma_f32_16x16x32_bf16(kB1, qf[s][1], sB, 0, 0, 0);
      int qrow = wq0 + s * 16 + i15;
      int kb = k0 + g8;
      float sa[8];
      if (maskt) {
#pragma unroll
        for (int r = 0; r < 4; ++r) {
          sa[r]     = (kb + r     <= qrow) ? sA[r] : -1e30f;
          sa[4 + r] = (kb + 4 + r <= qrow) ? sB[r] : -1e30f;
        }
      } else {
#pragma unroll
        for (int r = 0; r < 4; ++r) { sa[r] = sA[r]; sa[4 + r] = sB[r]; }
      }
      float tmx = sa[0];
#pragma unroll
      for (int r = 1; r < 8; ++r) tmx = fmaxf(tmx, sa[r]);
      tmx = fmaxf(tmx, __shfl_xor(tmx, 16));
      tmx = fmaxf(tmx, __shfl_xor(tmx, 32));
      float mnew = fmaxf(mrun[s], tmx);
      float scl = __expf(mrun[s] - mnew);
      float ps = 0.f;
      s16x8 pf;
#pragma unroll
      for (int r = 0; r < 8; ++r) {
        float p = __expf(sa[r] - mnew);
        ps += p;
        pf[r] = f2bf(p);
      }
      ps += __shfl_xor(ps, 16);
      ps += __shfl_xor(ps, 32);
      lrun[s] = lrun[s] * scl + ps;
      mrun[s] = mnew;
#pragma unroll
      for (int mt = 0; mt < 4; ++mt) {
#pragma unroll
        for (int r = 0; r < 4; ++r) oacc[s][mt][r] *= scl;
        oacc[s][mt] = __builtin_amdgcn_mfma_f32_16x16x32_bf16(vf[mt], pf, oacc[s][mt], 0, 0, 0);
      }
    }
  }
#pragma unroll
  for (int s = 0; s < 2; ++s) {
    float inv = 1.f / lrun[s];
    int qrow = wq0 + s * 16 + i15;
    short* op = Ob + ((size_t)(bb * T_ + qrow)) * C_ + hh * D_ + (g << 2);
#pragma unroll
    for (int mt = 0; mt < 4; ++mt) {
      s16x4 o4;
#pragma unroll
      for (int r = 0; r < 4; ++r) o4[r] = f2bf(oacc[s][mt][r] * inv);
      *(s16x4*)(op + mt * 16) = o4;
    }
  }
}

extern "C" void kernel_launch(void* const* d_in, const int* in_sizes, int n_in,
                              void* d_out, int out_size, void* d_ws, size_t ws_size,
                              hipStream_t stream) {
  const float* x     = (const float*)d_in[0];
  const float* ln1_w = (const float*)d_in[1];
  const float* ln1_b = (const float*)d_in[2];
  const float* qkv_w = (const float*)d_in[3];
  const float* qkv_b = (const float*)d_in[4];
  const float* out_w = (const float*)d_in[5];
  const float* out_b = (const float*)d_in[6];
  const float* ln2_w = (const float*)d_in[7];
  const float* ln2_b = (const float*)d_in[8];
  const float* ff1_w = (const float*)d_in[9];
  const float* ff1_b = (const float*)d_in[10];
  const float* ff2_w = (const float*)d_in[11];
  const float* ff2_b = (const float*)d_in[12];

  char* ws = (char*)d_ws;
  short* Wqkv = (short*)(ws + 0);                       // [2304,768]
  short* Wout = (short*)(ws + 3538944);                 // [768,768]
  short* Wff1 = (short*)(ws + 4718592);                 // [3072,768]
  short* Wff2 = (short*)(ws + 9437184);                 // [768,3072]
  short* Hbuf = (short*)(ws + 14155776);                // [8192,768] bf16; also aliases VT
  short* Qb   = (short*)(ws + 26738688);                // [B,H,T,D] bf16
  short* Kb   = Qb + 6291456;
  short* Vb   = Kb + 6291456;
  short* Ob   = Vb + 6291456;                           // [B,T,C] bf16
  short* FFH  = Qb;                                     // alias: [8192,3072] bf16 (Q/K/V/O dead)
  short* VT   = Hbuf;                                   // alias: [B,H,D,T] bf16 (Hbuf dead during attn)
  float* xout = (float*)d_out;                          // also x1 residual buffer

  wconv<<<dim3(24, 72), 256, 0, stream>>>(qkv_w, Wqkv, 768, 2304);
  wconv<<<dim3(24, 24), 256, 0, stream>>>(out_w, Wout, 768, 768);
  wconv<<<dim3(24, 96), 256, 0, stream>>>(ff1_w, Wff1, 768, 3072);
  wconv<<<dim3(96, 24), 256, 0, stream>>>(ff2_w, Wff2, 3072, 768);

  ln_kernel<<<8192, 256, 0, stream>>>(x, ln1_w, ln1_b, Hbuf);
  gemm_bt<0><<<dim3(64, 18), 256, 0, stream>>>(Hbuf, Wqkv, qkv_b, nullptr, nullptr,
                                               Qb, Kb, Vb, 8192, 2304, 768);
  vtrans<<<dim3(32, 48), 256, 0, stream>>>(Vb, VT);
  attn_kernel<<<dim3(16, 48), 256, 0, stream>>>(Qb, Kb, VT, Ob);
  gemm_bt<1><<<dim3(64, 6), 256, 0, stream>>>(Ob, Wout, out_b, x, xout,
                                              nullptr, nullptr, nullptr, 8192, 768, 768);
  ln_kernel<<<8192, 256, 0, stream>>>(xout, ln2_w, ln2_b, Hbuf);
  gemm_bt<2><<<dim3(64, 24), 256, 0, stream>>>(Hbuf, Wff1, ff1_b, nullptr, FFH,
                                               nullptr, nullptr, nullptr, 8192, 3072, 768);
  gemm_bt<3><<<dim3(64, 6), 256, 0, stream>>>(FFH, Wff2, ff2_b, xout, xout,
                                              nullptr, nullptr, nullptr, 8192, 768, 3072);
}

// Round 3
// 410.592 us; speedup vs baseline: 1.2276x; 1.0156x over previous
//
#include <hip/hip_runtime.h>
#include <cstdint>
#include <cstddef>

#define B_ 4
#define T_ 2048
#define C_ 768
#define H_ 12
#define D_ 64
#define FF_ 3072

typedef __attribute__((ext_vector_type(4))) float f32x4;
typedef __attribute__((ext_vector_type(8))) short s16x8;
typedef __attribute__((ext_vector_type(4))) short s16x4;

static __device__ __forceinline__ short f2bf(float f) {
  union { float fv; unsigned u; } v; v.fv = f;
  unsigned r = v.u + 0x7FFFu + ((v.u >> 16) & 1u);  // RNE
  return (short)(r >> 16);
}

// ---------- weight convert+transpose: in[K,N] f32 -> out[N,K] bf16 ----------
__global__ __launch_bounds__(256) void wconv(const float* __restrict__ in,
                                             short* __restrict__ out,
                                             int K, int N) {
  __shared__ float tile[32][33];
  int tk = blockIdx.x * 32, tn = blockIdx.y * 32;
  int lx = threadIdx.x & 31, ly = threadIdx.x >> 5;
#pragma unroll
  for (int i = 0; i < 4; ++i)
    tile[ly + i * 8][lx] = in[(size_t)(tk + ly + i * 8) * N + tn + lx];
  __syncthreads();
#pragma unroll
  for (int i = 0; i < 4; ++i)
    out[(size_t)(tn + ly + i * 8) * K + tk + lx] = f2bf(tile[lx][ly + i * 8]);
}

// ---------- layernorm: x[rows,768] f32 -> bf16 ----------
__global__ __launch_bounds__(256) void ln_kernel(const float* __restrict__ x,
                                                 const float* __restrict__ w,
                                                 const float* __restrict__ b,
                                                 short* __restrict__ out) {
  int row = blockIdx.x, tid = threadIdx.x;
  const float* xr = x + (size_t)row * 768;
  float v0 = xr[tid], v1 = xr[tid + 256], v2 = xr[tid + 512];
  float s = v0 + v1 + v2;
#pragma unroll
  for (int o = 32; o > 0; o >>= 1) s += __shfl_down(s, o);
  __shared__ float r1[4], r2[4];
  if ((tid & 63) == 0) r1[tid >> 6] = s;
  __syncthreads();
  float mean = (r1[0] + r1[1] + r1[2] + r1[3]) * (1.f / 768.f);
  float d0 = v0 - mean, d1 = v1 - mean, d2 = v2 - mean;
  float q = d0 * d0 + d1 * d1 + d2 * d2;
#pragma unroll
  for (int o = 32; o > 0; o >>= 1) q += __shfl_down(q, o);
  if ((tid & 63) == 0) r2[tid >> 6] = q;
  __syncthreads();
  float var = (r2[0] + r2[1] + r2[2] + r2[3]) * (1.f / 768.f);
  float rstd = rsqrtf(var + 1e-5f);
  short* orow = out + (size_t)row * 768;
  orow[tid]       = f2bf(d0 * rstd * w[tid]       + b[tid]);
  orow[tid + 256] = f2bf(d1 * rstd * w[tid + 256] + b[tid + 256]);
  orow[tid + 512] = f2bf(d2 * rstd * w[tid + 512] + b[tid + 512]);
}

// ---------- GEMM: C[M,N] = A[M,K](bf16) * Bt[N,K](bf16)^T + bias, fused epilogues ----------
// MODE 0: qkv scatter (bias, q*=0.125); Q,K -> [B,H,T,D]; V -> TRANSPOSED [B,H,D,T]
// MODE 1/3: bias + residual(res f32) -> f32 out
// MODE 2: bias + relu -> bf16 out
template <int MODE>
__global__ __launch_bounds__(256) void gemm_bt(
    const short* __restrict__ A, const short* __restrict__ Bt,
    const float* __restrict__ bias, const float* __restrict__ res,
    void* __restrict__ out,
    short* __restrict__ dq, short* __restrict__ dk, short* __restrict__ dv,
    int M, int N, int K) {
  __shared__ short As[128 * 32];
  __shared__ short Bs[128 * 32];
  int tid = threadIdx.x;
  int lane = tid & 63;
  int wm = tid >> 7;
  int wn = (tid >> 6) & 1;
  const short* Ab = A + (size_t)blockIdx.x * 128 * K;
  const short* Bb = Bt + (size_t)blockIdx.y * 128 * K;
  f32x4 acc[4][4] = {};
  int i15 = lane & 15, g8 = (lane >> 4) << 3;
  int nk = K >> 5;
  for (int kt = 0; kt < nk; ++kt) {
    int kof = kt << 5;
#pragma unroll
    for (int i = 0; i < 2; ++i) {
      int s = tid + i * 256;
      int row = s >> 2, kk = (s & 3) << 3;
      __builtin_amdgcn_global_load_lds(
          (const __attribute__((address_space(1))) unsigned*)(Ab + (size_t)row * K + kof + kk),
          (__attribute__((address_space(3))) unsigned*)(As + s * 8), 16, 0, 0);
      __builtin_amdgcn_global_load_lds(
          (const __attribute__((address_space(1))) unsigned*)(Bb + (size_t)row * K + kof + kk),
          (__attribute__((address_space(3))) unsigned*)(Bs + s * 8), 16, 0, 0);
    }
    __syncthreads();
    s16x8 af[4], bfr[4];
#pragma unroll
    for (int m = 0; m < 4; ++m)
      af[m] = *(const s16x8*)(As + (wm * 64 + m * 16 + i15) * 32 + g8);
#pragma unroll
    for (int n = 0; n < 4; ++n)
      bfr[n] = *(const s16x8*)(Bs + (wn * 64 + n * 16 + i15) * 32 + g8);
#pragma unroll
    for (int m = 0; m < 4; ++m)
#pragma unroll
      for (int n = 0; n < 4; ++n)
        acc[m][n] = __builtin_amdgcn_mfma_f32_16x16x32_bf16(af[m], bfr[n], acc[m][n], 0, 0, 0);
    __syncthreads();
  }
  int row0 = blockIdx.x * 128 + wm * 64;
  int col0 = blockIdx.y * 128 + wn * 64;
  int g4 = (lane >> 4) << 2;
#pragma unroll
  for (int m = 0; m < 4; ++m) {
#pragma unroll
    for (int n = 0; n < 4; ++n) {
      int col = col0 + n * 16 + i15;
      float bv = bias[col];
      float v4[4];
#pragma unroll
      for (int r = 0; r < 4; ++r) v4[r] = acc[m][n][r] + bv;
      int rbase = row0 + m * 16 + g4;
      if constexpr (MODE == 0) {
        int sect = col / 768;            // 0=q 1=k 2=v
        int wi = col - sect * 768;
        int hh = wi >> 6, dd = wi & 63;
        int bb = rbase >> 11, tt = rbase & 2047;
        if (sect == 2) {
          s16x4 o4;
#pragma unroll
          for (int r = 0; r < 4; ++r) o4[r] = f2bf(v4[r]);
          *(s16x4*)(dv + ((size_t)(bb * H_ + hh) * D_ + dd) * T_ + tt) = o4;
        } else {
          short* dst = (sect == 0 ? dq : dk) + ((size_t)(bb * H_ + hh) * T_ + tt) * D_ + dd;
          float sc = sect == 0 ? 0.125f : 1.f;
#pragma unroll
          for (int r = 0; r < 4; ++r) dst[(size_t)r * D_] = f2bf(v4[r] * sc);
        }
      } else if constexpr (MODE == 2) {
#pragma unroll
        for (int r = 0; r < 4; ++r)
          ((short*)out)[(size_t)(rbase + r) * N + col] = f2bf(v4[r] > 0.f ? v4[r] : 0.f);
      } else {
#pragma unroll
        for (int r = 0; r < 4; ++r)
          ((float*)out)[(size_t)(rbase + r) * N + col] = v4[r] + res[(size_t)(rbase + r) * N + col];
      }
    }
  }
}

// ---------- causal flash attention (no LDS, register-double-buffered K/V) ----------
// Q/K [B,H,T,D] (Q pre-scaled 1/8), VT [B,H,D,T] bf16 -> Ob [B,T,C] bf16.
// 4 waves/block, each wave owns 32 q-rows (2x16 subtiles); key tiles of 32.
__global__ __launch_bounds__(256, 3) void attn_kernel(const short* __restrict__ Qb,
                                                      const short* __restrict__ Kb,
                                                      const short* __restrict__ VTb,
                                                      short* __restrict__ Ob) {
  int bx = gridDim.x - 1 - blockIdx.x;   // longest blocks first
  int bh = blockIdx.y;
  int bb = bh / H_, hh = bh - bb * H_;
  int tid = threadIdx.x, lane = tid & 63, wv = tid >> 6;
  int wq0 = bx * 128 + wv * 32;
  const short* Qp = Qb + (size_t)bh * T_ * D_;
  const short* Kp = Kb + (size_t)bh * T_ * D_;
  const short* Vp = VTb + (size_t)bh * D_ * T_;
  int i15 = lane & 15, g = lane >> 4, g8 = g << 3;
  s16x8 qf[2][2];
#pragma unroll
  for (int s = 0; s < 2; ++s) {
    int qrow = wq0 + s * 16 + i15;
    qf[s][0] = *(const s16x8*)(Qp + (size_t)qrow * D_ + g8);
    qf[s][1] = *(const s16x8*)(Qp + (size_t)qrow * D_ + 32 + g8);
  }
  f32x4 oacc[2][4] = {};
  float mrun[2] = {-1e30f, -1e30f}, lrun[2] = {0.f, 0.f};
  int keyA0 = ((i15 >> 2) << 3) + (i15 & 3);  // perm: A-row i -> key (i/4)*8 + i%4
  int nt = (wq0 >> 5) + 1;
  // prefetch tile 0
  s16x8 ka0, ka1, kb0, kb1, va0, va1, va2, va3;
  {
    const short* KA = Kp + (size_t)keyA0 * D_;
    ka0 = *(const s16x8*)(KA + g8);
    ka1 = *(const s16x8*)(KA + 32 + g8);
    const short* KB = KA + 4 * D_;
    kb0 = *(const s16x8*)(KB + g8);
    kb1 = *(const s16x8*)(KB + 32 + g8);
    va0 = *(const s16x8*)(Vp + (size_t)(0 * 16 + i15) * T_ + g8);
    va1 = *(const s16x8*)(Vp + (size_t)(1 * 16 + i15) * T_ + g8);
    va2 = *(const s16x8*)(Vp + (size_t)(2 * 16 + i15) * T_ + g8);
    va3 = *(const s16x8*)(Vp + (size_t)(3 * 16 + i15) * T_ + g8);
  }
#pragma unroll 2
  for (int kt = 0; kt < nt; ++kt) {
    int k0 = kt << 5;
    bool last = (kt == nt - 1);
    int kn = last ? 0 : (k0 + 32);   // dummy (cached) prefetch on last trip
    // ---- issue next-tile loads (latency hidden under current compute) ----
    const short* KA = Kp + (size_t)(kn + keyA0) * D_;
    s16x8 nka0 = *(const s16x8*)(KA + g8);
    s16x8 nka1 = *(const s16x8*)(KA + 32 + g8);
    const short* KB = KA + 4 * D_;
    s16x8 nkb0 = *(const s16x8*)(KB + g8);
    s16x8 nkb1 = *(const s16x8*)(KB + 32 + g8);
    s16x8 nva0 = *(const s16x8*)(Vp + (size_t)(0 * 16 + i15) * T_ + kn + g8);
    s16x8 nva1 = *(const s16x8*)(Vp + (size_t)(1 * 16 + i15) * T_ + kn + g8);
    s16x8 nva2 = *(const s16x8*)(Vp + (size_t)(2 * 16 + i15) * T_ + kn + g8);
    s16x8 nva3 = *(const s16x8*)(Vp + (size_t)(3 * 16 + i15) * T_ + kn + g8);
    // ---- compute current tile ----
#pragma unroll
    for (int s = 0; s < 2; ++s) {
      f32x4 sA = {}, sB = {};
      __builtin_amdgcn_s_setprio(1);
      sA = __builtin_amdgcn_mfma_f32_16x16x32_bf16(ka0, qf[s][0], sA, 0, 0, 0);
      sA = __builtin_amdgcn_mfma_f32_16x16x32_bf16(ka1, qf[s][1], sA, 0, 0, 0);
      sB = __builtin_amdgcn_mfma_f32_16x16x32_bf16(kb0, qf[s][0], sB, 0, 0, 0);
      sB = __builtin_amdgcn_mfma_f32_16x16x32_bf16(kb1, qf[s][1], sB, 0, 0, 0);
      __builtin_amdgcn_s_setprio(0);
      int qrow = wq0 + s * 16 + i15;
      int kb = k0 + g8;
      float sa[8];
      if (last) {
#pragma unroll
        for (int r = 0; r < 4; ++r) {
          sa[r]     = (kb + r     <= qrow) ? sA[r] : -1e30f;
          sa[4 + r] = (kb + 4 + r <= qrow) ? sB[r] : -1e30f;
        }
      } else {
#pragma unroll
        for (int r = 0; r < 4; ++r) { sa[r] = sA[r]; sa[4 + r] = sB[r]; }
      }
      float tmx = sa[0];
#pragma unroll
      for (int r = 1; r < 8; ++r) tmx = fmaxf(tmx, sa[r]);
      tmx = fmaxf(tmx, __shfl_xor(tmx, 16));
      tmx = fmaxf(tmx, __shfl_xor(tmx, 32));
      bool defer = __all(tmx - mrun[s] <= 8.f);   // T13: skip rescale most trips
      float mnew = defer ? mrun[s] : fmaxf(mrun[s], tmx);
      float ps = 0.f;
      s16x8 pf;
#pragma unroll
      for (int r = 0; r < 8; ++r) {
        float p = __expf(sa[r] - mnew);
        ps += p;
        pf[r] = f2bf(p);
      }
      ps += __shfl_xor(ps, 16);
      ps += __shfl_xor(ps, 32);
      if (defer) {
        lrun[s] += ps;
      } else {
        float scl = __expf(mrun[s] - mnew);
        lrun[s] = lrun[s] * scl + ps;
        mrun[s] = mnew;
#pragma unroll
        for (int mt = 0; mt < 4; ++mt)
#pragma unroll
          for (int r = 0; r < 4; ++r) oacc[s][mt][r] *= scl;
      }
      __builtin_amdgcn_s_setprio(1);
      oacc[s][0] = __builtin_amdgcn_mfma_f32_16x16x32_bf16(va0, pf, oacc[s][0], 0, 0, 0);
      oacc[s][1] = __builtin_amdgcn_mfma_f32_16x16x32_bf16(va1, pf, oacc[s][1], 0, 0, 0);
      oacc[s][2] = __builtin_amdgcn_mfma_f32_16x16x32_bf16(va2, pf, oacc[s][2], 0, 0, 0);
      oacc[s][3] = __builtin_amdgcn_mfma_f32_16x16x32_bf16(va3, pf, oacc[s][3], 0, 0, 0);
      __builtin_amdgcn_s_setprio(0);
    }
    // ---- rotate buffers ----
    ka0 = nka0; ka1 = nka1; kb0 = nkb0; kb1 = nkb1;
    va0 = nva0; va1 = nva1; va2 = nva2; va3 = nva3;
  }
#pragma unroll
  for (int s = 0; s < 2; ++s) {
    float inv = 1.f / lrun[s];
    int qrow = wq0 + s * 16 + i15;
    short* op = Ob + ((size_t)(bb * T_ + qrow)) * C_ + hh * D_ + (g << 2);
#pragma unroll
    for (int mt = 0; mt < 4; ++mt) {
      s16x4 o4;
#pragma unroll
      for (int r = 0; r < 4; ++r) o4[r] = f2bf(oacc[s][mt][r] * inv);
      *(s16x4*)(op + mt * 16) = o4;
    }
  }
}

extern "C" void kernel_launch(void* const* d_in, const int* in_sizes, int n_in,
                              void* d_out, int out_size, void* d_ws, size_t ws_size,
                              hipStream_t stream) {
  const float* x     = (const float*)d_in[0];
  const float* ln1_w = (const float*)d_in[1];
  const float* ln1_b = (const float*)d_in[2];
  const float* qkv_w = (const float*)d_in[3];
  const float* qkv_b = (const float*)d_in[4];
  const float* out_w = (const float*)d_in[5];
  const float* out_b = (const float*)d_in[6];
  const float* ln2_w = (const float*)d_in[7];
  const float* ln2_b = (const float*)d_in[8];
  const float* ff1_w = (const float*)d_in[9];
  const float* ff1_b = (const float*)d_in[10];
  const float* ff2_w = (const float*)d_in[11];
  const float* ff2_b = (const float*)d_in[12];

  char* ws = (char*)d_ws;
  short* Wqkv = (short*)(ws + 0);                       // [2304,768]
  short* Wout = (short*)(ws + 3538944);                 // [768,768]
  short* Wff1 = (short*)(ws + 4718592);                 // [3072,768]
  short* Wff2 = (short*)(ws + 9437184);                 // [768,3072]
  short* Hbuf = (short*)(ws + 14155776);                // [8192,768] bf16
  short* Qb   = (short*)(ws + 26738688);                // [B,H,T,D] bf16
  short* Kb   = Qb + 6291456;
  short* VT   = Kb + 6291456;                           // [B,H,D,T] bf16 (V stored transposed)
  short* Ob   = VT + 6291456;                           // [B,T,C] bf16
  short* FFH  = Qb;                                     // alias: [8192,3072] bf16 (Q/K/V/O dead)
  float* xout = (float*)d_out;                          // also x1 residual buffer

  wconv<<<dim3(24, 72), 256, 0, stream>>>(qkv_w, Wqkv, 768, 2304);
  wconv<<<dim3(24, 24), 256, 0, stream>>>(out_w, Wout, 768, 768);
  wconv<<<dim3(24, 96), 256, 0, stream>>>(ff1_w, Wff1, 768, 3072);
  wconv<<<dim3(96, 24), 256, 0, stream>>>(ff2_w, Wff2, 3072, 768);

  ln_kernel<<<8192, 256, 0, stream>>>(x, ln1_w, ln1_b, Hbuf);
  gemm_bt<0><<<dim3(64, 18), 256, 0, stream>>>(Hbuf, Wqkv, qkv_b, nullptr, nullptr,
                                               Qb, Kb, VT, 8192, 2304, 768);
  attn_kernel<<<dim3(16, 48), 256, 0, stream>>>(Qb, Kb, VT, Ob);
  gemm_bt<1><<<dim3(64, 6), 256, 0, stream>>>(Ob, Wout, out_b, x, xout,
                                              nullptr, nullptr, nullptr, 8192, 768, 768);
  ln_kernel<<<8192, 256, 0, stream>>>(xout, ln2_w, ln2_b, Hbuf);
  gemm_bt<2><<<dim3(64, 24), 256, 0, stream>>>(Hbuf, Wff1, ff1_b, nullptr, FFH,
                                               nullptr, nullptr, nullptr, 8192, 3072, 768);
  gemm_bt<3><<<dim3(64, 6), 256, 0, stream>>>(FFH, Wff2, ff2_b, xout, xout,
                                              nullptr, nullptr, nullptr, 8192, 768, 3072);
}